// Round 3
// 805.549 us; speedup vs baseline: 1.0473x; 1.0473x over previous
//
#include <hip/hip_runtime.h>
#include <cmath>
#include <type_traits>

typedef unsigned short u16;
typedef float  f32x4 __attribute__((ext_vector_type(4)));
typedef short  s16x8 __attribute__((ext_vector_type(8)));
typedef __bf16 b16x8 __attribute__((ext_vector_type(8)));

#define GLOBAL_AS __attribute__((address_space(1)))
#define LDS_AS    __attribute__((address_space(3)))

constexpr int S_  = 1536;
constexpr int B_  = 2;
constexpr int D_  = 768;
constexpr int H_  = 24;
constexpr int DH_ = 32;
constexpr int FF_ = 3072;
constexpr int N_  = S_ * B_;      // 3072 tokens, row = s*B + b
constexpr int D3_ = 3 * D_;       // 2304
constexpr float SCALE_ = 0.17677669529663687f;  // 1/sqrt(32)

// ---- MFMA wrapper: works whether the builtin takes short8 or bf16x8 ----
template <typename T>
static __device__ inline auto mfma_try(T a, T b, f32x4 c, int)
    -> decltype(__builtin_amdgcn_mfma_f32_16x16x32_bf16(a, b, c, 0, 0, 0)) {
  return __builtin_amdgcn_mfma_f32_16x16x32_bf16(a, b, c, 0, 0, 0);
}
template <typename T>
static __device__ inline f32x4 mfma_try(T a, T b, f32x4 c, long) {
  b16x8 ab = __builtin_bit_cast(b16x8, a);
  b16x8 bb = __builtin_bit_cast(b16x8, b);
  return __builtin_amdgcn_mfma_f32_16x16x32_bf16(ab, bb, c, 0, 0, 0);
}
static __device__ inline f32x4 mfma_bf16(s16x8 a, s16x8 b, f32x4 c) {
  return mfma_try(a, b, c, 0);
}

// native RNE f32->bf16 (compiler emits v_cvt_pk_bf16_f32; cheaper than manual)
static __device__ inline u16 f2bf(float f) {
  return __builtin_bit_cast(u16, (__bf16)f);
}

static __device__ inline float rmax16(float v) {
  v = fmaxf(v, __shfl_xor(v, 1));
  v = fmaxf(v, __shfl_xor(v, 2));
  v = fmaxf(v, __shfl_xor(v, 4));
  v = fmaxf(v, __shfl_xor(v, 8));
  return v;
}
static __device__ inline float rsum16(float v) {
  v += __shfl_xor(v, 1);
  v += __shfl_xor(v, 2);
  v += __shfl_xor(v, 4);
  v += __shfl_xor(v, 8);
  return v;
}

// ---- weight fp32 -> bf16 conversion, BOTH layers in one launch ----
__global__ void convert_weights_kernel(const float* __restrict__ q0, const float* __restrict__ o0,
                                       const float* __restrict__ f0, const float* __restrict__ p0,
                                       const float* __restrict__ q1, const float* __restrict__ o1,
                                       const float* __restrict__ f1, const float* __restrict__ p1,
                                       u16* __restrict__ dst) {
  constexpr int C0 = D3_ * D_;            // 1769472
  constexpr int C1 = C0 + D_ * D_;        // 2359296
  constexpr int C2 = C1 + FF_ * D_;       // 4718592
  constexpr int C3 = C2 + D_ * FF_;       // 7077888
  const int l = blockIdx.y;
  int i4 = (blockIdx.x * 256 + threadIdx.x) * 4;
  if (i4 >= C3) return;
  const float* wqkv  = l ? q1 : q0;
  const float* wo    = l ? o1 : o0;
  const float* wfc   = l ? f1 : f0;
  const float* wproj = l ? p1 : p0;
  const float* src; int off;
  if (i4 < C0)      { src = wqkv;  off = i4; }
  else if (i4 < C1) { src = wo;    off = i4 - C0; }
  else if (i4 < C2) { src = wfc;   off = i4 - C1; }
  else              { src = wproj; off = i4 - C2; }
  float4 v = *(const float4*)(src + off);
  ushort4 o;
  o.x = f2bf(v.x); o.y = f2bf(v.y); o.z = f2bf(v.z); o.w = f2bf(v.w);
  *(ushort4*)(dst + (size_t)l * C3 + i4) = o;
}

// ---- fused embedding + layer0-LN1: x = wte[id]+wpe[pos]; h = LN(x) ----
// 1 wave per token (4 waves/block), saves one full x read+h write pass.
__global__ void embed_ln_kernel(const int* __restrict__ ids, const int* __restrict__ pos,
                                const float* __restrict__ wte, const float* __restrict__ wpe,
                                const float* __restrict__ w, const float* __restrict__ b,
                                float* __restrict__ x, u16* __restrict__ h) {
  int wid = threadIdx.x >> 6, lane = threadIdx.x & 63;
  int tok = blockIdx.x * 4 + wid;
  int s = tok >> 1, bb = tok & 1;
  int t = ids[bb * S_ + s];
  int p = pos[bb * S_ + s];
  const float* wt = wte + (size_t)t * D_;
  const float* wp = wpe + (size_t)p * D_;
  float* xr = x + (size_t)tok * D_;
  float4 v[3];
  float sum = 0.f, ss = 0.f;
#pragma unroll
  for (int c = 0; c < 3; ++c) {
    int d = c * 256 + lane * 4;
    float4 a = *(const float4*)(wt + d);
    float4 e = *(const float4*)(wp + d);
    a.x += e.x; a.y += e.y; a.z += e.z; a.w += e.w;
    v[c] = a;
    *(float4*)(xr + d) = a;
    sum += a.x + a.y + a.z + a.w;
    ss  += a.x * a.x + a.y * a.y + a.z * a.z + a.w * a.w;
  }
#pragma unroll
  for (int m = 1; m <= 32; m <<= 1) { sum += __shfl_xor(sum, m); ss += __shfl_xor(ss, m); }
  float mu = sum * (1.0f / D_);
  float var = ss * (1.0f / D_) - mu * mu;
  float rs = rsqrtf(var + 1e-5f);
#pragma unroll
  for (int c = 0; c < 3; ++c) {
    int d = c * 256 + lane * 4;
    float4 wv = *(const float4*)(w + d);
    float4 bv = *(const float4*)(b + d);
    ushort4 o;
    o.x = f2bf((v[c].x - mu) * rs * wv.x + bv.x);
    o.y = f2bf((v[c].y - mu) * rs * wv.y + bv.y);
    o.z = f2bf((v[c].z - mu) * rs * wv.z + bv.z);
    o.w = f2bf((v[c].w - mu) * rs * wv.w + bv.w);
    *(ushort4*)(h + (size_t)tok * D_ + d) = o;
  }
}

// ---- LayerNorm: 1 wave per token, OUT = u16 (bf16) or float ----
template <typename OUT>
__global__ void ln_kernel(const float* __restrict__ x, const float* __restrict__ w,
                          const float* __restrict__ b, OUT* __restrict__ out) {
  int wid = threadIdx.x >> 6, lane = threadIdx.x & 63;
  int tok = blockIdx.x * 4 + wid;
  const float* xr = x + (size_t)tok * D_;
  float4 v[3];
  float s = 0.f, ss = 0.f;
#pragma unroll
  for (int c = 0; c < 3; ++c) {
    v[c] = *(const float4*)(xr + c * 256 + lane * 4);
    s  += v[c].x + v[c].y + v[c].z + v[c].w;
    ss += v[c].x * v[c].x + v[c].y * v[c].y + v[c].z * v[c].z + v[c].w * v[c].w;
  }
#pragma unroll
  for (int m = 1; m <= 32; m <<= 1) { s += __shfl_xor(s, m); ss += __shfl_xor(ss, m); }
  float mu = s * (1.0f / D_);
  float var = ss * (1.0f / D_) - mu * mu;
  float rs = rsqrtf(var + 1e-5f);
#pragma unroll
  for (int c = 0; c < 3; ++c) {
    int d = c * 256 + lane * 4;
    float4 wv = *(const float4*)(w + d);
    float4 bv = *(const float4*)(b + d);
    float o0 = (v[c].x - mu) * rs * wv.x + bv.x;
    float o1 = (v[c].y - mu) * rs * wv.y + bv.y;
    float o2 = (v[c].z - mu) * rs * wv.z + bv.z;
    float o3 = (v[c].w - mu) * rs * wv.w + bv.w;
    if constexpr (std::is_same_v<OUT, u16>) {
      ushort4 o; o.x = f2bf(o0); o.y = f2bf(o1); o.z = f2bf(o2); o.w = f2bf(o3);
      *(ushort4*)(out + (size_t)tok * D_ + d) = o;
    } else {
      float4 o; o.x = o0; o.y = o1; o.z = o2; o.w = o3;
      *(float4*)(out + (size_t)tok * D_ + d) = o;
    }
  }
}

// ---- Generic MFMA GEMM: C[tok, feat] = X[tok,:] . W[feat,:] + bias ----
// BK=64, global_load_lds(16B) staging, XOR-3 chunk swizzle (conflict-free
// ds_read_b128).  EPI 0: scatter to q/k/vt (bf16; q pre-scaled by SCALE_)
// EPI 1: += residual, fp32 in/out    EPI 2: GELU -> bf16 (feat dim = FF_)
template <int BM, int BN, int EPI>
__launch_bounds__(256, 3)
__global__ void gemm_kernel(const u16* __restrict__ X, const u16* __restrict__ W,
                            const float* __restrict__ bias, int K,
                            u16* __restrict__ o0, u16* __restrict__ o1,
                            u16* __restrict__ o2, float* __restrict__ xio) {
  constexpr int BK = 64;
  constexpr int WM = BM / 2, WN = BN / 2, TM = WM / 16, TN = WN / 16;
  __shared__ u16 As[BM * BK];
  __shared__ u16 Bs[BN * BK];
  const int tid = threadIdx.x;
  const int wid = tid >> 6, lane = tid & 63;
  const int col = lane & 15, quad = lane >> 4;
  const int wm = wid & 1, wn = wid >> 1;
  const int rowA0 = blockIdx.x * BM;
  const int rowB0 = blockIdx.y * BN;

  f32x4 zz = {0.f, 0.f, 0.f, 0.f};
  f32x4 acc[TM][TN];
#pragma unroll
  for (int i = 0; i < TM; ++i)
#pragma unroll
    for (int j = 0; j < TN; ++j) acc[i][j] = zz;

  for (int k0 = 0; k0 < K; k0 += BK) {
#pragma unroll
    for (int it = 0; it < BM / 32; ++it) {
      int bs = (it * 4 + wid) * 64;          // wave-uniform base slot
      int slot = bs + lane;
      int r = slot >> 3;
      int c = (slot & 7) ^ (r & 7);
      const u16* g = &X[(size_t)(rowA0 + r) * K + k0 + c * 8];
      __builtin_amdgcn_global_load_lds((const GLOBAL_AS unsigned int*)g,
                                       (LDS_AS unsigned int*)&As[bs * 8], 16, 0, 0);
    }
#pragma unroll
    for (int it = 0; it < BN / 32; ++it) {
      int bs = (it * 4 + wid) * 64;
      int slot = bs + lane;
      int r = slot >> 3;
      int c = (slot & 7) ^ (r & 7);
      const u16* g = &W[(size_t)(rowB0 + r) * K + k0 + c * 8];
      __builtin_amdgcn_global_load_lds((const GLOBAL_AS unsigned int*)g,
                                       (LDS_AS unsigned int*)&Bs[bs * 8], 16, 0, 0);
    }
    __syncthreads();
#pragma unroll
    for (int kb = 0; kb < 2; ++kb) {
      s16x8 af[TM], bf[TN];
#pragma unroll
      for (int ti = 0; ti < TM; ++ti) {
        int row = wm * WM + ti * 16 + col;
        af[ti] = *(const s16x8*)&As[row * BK + ((kb * 4 + quad) ^ (row & 7)) * 8];
      }
#pragma unroll
      for (int tj = 0; tj < TN; ++tj) {
        int row = wn * WN + tj * 16 + col;
        bf[tj] = *(const s16x8*)&Bs[row * BK + ((kb * 4 + quad) ^ (row & 7)) * 8];
      }
#pragma unroll
      for (int ti = 0; ti < TM; ++ti)
#pragma unroll
        for (int tj = 0; tj < TN; ++tj)
          acc[ti][tj] = mfma_bf16(af[ti], bf[tj], acc[ti][tj]);
    }
    __syncthreads();
  }

  const int tokBase  = rowA0 + wm * WM + quad * 4;
  const int featBase = rowB0 + wn * WN + col;
#pragma unroll
  for (int ti = 0; ti < TM; ++ti) {
#pragma unroll
    for (int tj = 0; tj < TN; ++tj) {
      int feat = featBase + tj * 16;
      float bv = bias[feat];
#pragma unroll
      for (int r = 0; r < 4; ++r) {
        int tok = tokBase + ti * 16 + r;
        float v = acc[ti][tj][r] + bv;
        if constexpr (EPI == 0) {
          int hh = feat / 96;
          int rem = feat - hh * 96;
          int comp = rem >> 5, d = rem & 31;
          int s = tok >> 1, bb = tok & 1;
          int bh = bb * H_ + hh;
          if (comp == 0)      o0[((size_t)bh * S_ + s) * DH_ + d] = f2bf(v * SCALE_);
          else if (comp == 1) o1[((size_t)bh * S_ + s) * DH_ + d] = f2bf(v);
          else                o2[((size_t)bh * DH_ + d) * S_ + s] = f2bf(v);
        } else if constexpr (EPI == 1) {
          float* p = xio + (size_t)tok * D_ + feat;
          *p = *p + v;
        } else {
          float g = 0.5f * v * (1.0f + erff(v * 0.70710678118654752f));
          o0[(size_t)tok * FF_ + feat] = f2bf(g);
        }
      }
    }
  }
}

// ---- flash attention: grid (S/64, B*H), block 256; each wave owns 16 q-rows.
// q is PRE-SCALED by 1/sqrt(DH) at the QKV epilogue.
// Bulk: 64-key unmasked iterations (no cmp/select, shuffle reductions
// amortized over 4 score regs). Tail: <=2 masked 32-key iterations.
// All LDS traffic (P relayout) is wave-private -> NO block barriers.
__launch_bounds__(256)
__global__ void attn_kernel(const u16* __restrict__ q, const u16* __restrict__ k,
                            const u16* __restrict__ vt, u16* __restrict__ ctx) {
  __shared__ u16 Plds[4][16 * 72];
  const int tid = threadIdx.x;
  const int wid = tid >> 6, lane = tid & 63;
  const int col = lane & 15, quad = lane >> 4;
  const int bh = blockIdx.y;
  const int bb = bh / H_, hh = bh - bb * H_;
  const u16* qb = q  + (size_t)bh * S_ * DH_;
  const u16* kb = k  + (size_t)bh * S_ * DH_;
  const u16* vb = vt + (size_t)bh * DH_ * S_;
  const int q0 = blockIdx.x * 64 + wid * 16;
  u16* P = &Plds[wid][0];

  s16x8 qf = *(const s16x8*)&qb[(q0 + col) * DH_ + quad * 8];
  f32x4 zz = {0.f, 0.f, 0.f, 0.f};
  f32x4 o0 = zz, o1 = zz;
  float mr[4] = {-1e30f, -1e30f, -1e30f, -1e30f};
  float lr[4] = {0.f, 0.f, 0.f, 0.f};

  // ---- bulk: fully-unmasked 64-key blocks (k0+63 < q0 <= min qq) ----
  const int fullEnd = (q0 >> 6) << 6;
  for (int k0 = 0; k0 < fullEnd; k0 += 64) {
    s16x8 kf0 = *(const s16x8*)&kb[(k0 +  0 + col) * DH_ + quad * 8];
    s16x8 kf1 = *(const s16x8*)&kb[(k0 + 16 + col) * DH_ + quad * 8];
    s16x8 kf2 = *(const s16x8*)&kb[(k0 + 32 + col) * DH_ + quad * 8];
    s16x8 kf3 = *(const s16x8*)&kb[(k0 + 48 + col) * DH_ + quad * 8];
    f32x4 s0 = mfma_bf16(qf, kf0, zz);
    f32x4 s1 = mfma_bf16(qf, kf1, zz);
    f32x4 s2 = mfma_bf16(qf, kf2, zz);
    f32x4 s3 = mfma_bf16(qf, kf3, zz);
#pragma unroll
    for (int r = 0; r < 4; ++r) {
      float a0 = s0[r], a1 = s1[r], a2 = s2[r], a3 = s3[r];
      float cm = rmax16(fmaxf(fmaxf(a0, a1), fmaxf(a2, a3)));
      float nm = fmaxf(mr[r], cm);
      float al = __expf(mr[r] - nm);
      float p0 = __expf(a0 - nm);
      float p1 = __expf(a1 - nm);
      float p2 = __expf(a2 - nm);
      float p3 = __expf(a3 - nm);
      float rs = rsum16((p0 + p1) + (p2 + p3));
      lr[r] = lr[r] * al + rs;
      mr[r] = nm;
      o0[r] *= al; o1[r] *= al;
      int ro = (quad * 4 + r) * 72;
      P[ro + col]      = f2bf(p0);
      P[ro + col + 16] = f2bf(p1);
      P[ro + col + 32] = f2bf(p2);
      P[ro + col + 48] = f2bf(p3);
    }
    __builtin_amdgcn_wave_barrier();
    __builtin_amdgcn_s_waitcnt(0xc07f);  // lgkmcnt(0): P writes retired
    __builtin_amdgcn_wave_barrier();
    s16x8 pf0 = *(const s16x8*)&P[col * 72 + quad * 8];
    s16x8 pf1 = *(const s16x8*)&P[col * 72 + 32 + quad * 8];
    s16x8 va0 = *(const s16x8*)&vb[(size_t)col * S_ + k0 + quad * 8];
    s16x8 va1 = *(const s16x8*)&vb[(size_t)col * S_ + k0 + 32 + quad * 8];
    s16x8 vc0 = *(const s16x8*)&vb[(size_t)(16 + col) * S_ + k0 + quad * 8];
    s16x8 vc1 = *(const s16x8*)&vb[(size_t)(16 + col) * S_ + k0 + 32 + quad * 8];
    o0 = mfma_bf16(pf0, va0, o0);
    o0 = mfma_bf16(pf1, va1, o0);
    o1 = mfma_bf16(pf0, vc0, o1);
    o1 = mfma_bf16(pf1, vc1, o1);
    __builtin_amdgcn_wave_barrier();
  }

  // ---- tail: masked 32-key blocks up to q0+16 ----
  const int kend = q0 + 16;
  for (int k0 = fullEnd; k0 < kend; k0 += 32) {
    s16x8 kf0 = *(const s16x8*)&kb[(k0 + col) * DH_ + quad * 8];
    s16x8 kf1 = *(const s16x8*)&kb[(k0 + 16 + col) * DH_ + quad * 8];
    f32x4 s0 = mfma_bf16(qf, kf0, zz);
    f32x4 s1 = mfma_bf16(qf, kf1, zz);
#pragma unroll
    for (int r = 0; r < 4; ++r) {
      int qq = q0 + quad * 4 + r;
      float x0 = (k0 + col <= qq)      ? s0[r] : -10000.0f;
      float x1 = (k0 + 16 + col <= qq) ? s1[r] : -10000.0f;
      float cm = rmax16(fmaxf(x0, x1));
      float nm = fmaxf(mr[r], cm);
      float al = __expf(mr[r] - nm);
      float p0 = __expf(x0 - nm);
      float p1 = __expf(x1 - nm);
      float rs = rsum16(p0 + p1);
      lr[r] = lr[r] * al + rs;
      mr[r] = nm;
      o0[r] *= al; o1[r] *= al;
      int ro = (quad * 4 + r) * 72;
      P[ro + col]      = f2bf(p0);
      P[ro + col + 16] = f2bf(p1);
    }
    __builtin_amdgcn_wave_barrier();
    __builtin_amdgcn_s_waitcnt(0xc07f);
    __builtin_amdgcn_wave_barrier();
    s16x8 pf  = *(const s16x8*)&P[col * 72 + quad * 8];
    s16x8 vf0 = *(const s16x8*)&vb[(size_t)col * S_ + k0 + quad * 8];
    s16x8 vf1 = *(const s16x8*)&vb[(size_t)(16 + col) * S_ + k0 + quad * 8];
    o0 = mfma_bf16(pf, vf0, o0);
    o1 = mfma_bf16(pf, vf1, o1);
    __builtin_amdgcn_wave_barrier();
  }

#pragma unroll
  for (int r = 0; r < 4; ++r) {
    float inv = 1.0f / lr[r];
    int qq = q0 + quad * 4 + r;
    size_t base = ((size_t)qq * B_ + bb) * D_ + hh * DH_;
    ctx[base + col]      = f2bf(o0[r] * inv);
    ctx[base + 16 + col] = f2bf(o1[r] * inv);
  }
}

extern "C" void kernel_launch(void* const* d_in, const int* in_sizes, int n_in,
                              void* d_out, int out_size, void* d_ws, size_t ws_size,
                              hipStream_t stream) {
  const int*   ids = (const int*)d_in[0];
  const int*   pos = (const int*)d_in[1];
  const float* wte = (const float*)d_in[3];
  const float* wpe = (const float*)d_in[4];
  const float* lnf_w = (const float*)d_in[29];
  const float* lnf_b = (const float*)d_in[30];

  // workspace layout (bytes)
  char* ws = (char*)d_ws;
  constexpr size_t SZ_X   = (size_t)N_ * D_ * 4;       // 9437184
  constexpr size_t SZ_H   = (size_t)N_ * D_ * 2;       // 4718592
  constexpr size_t SZ_QKV = (size_t)B_ * H_ * S_ * DH_ * 2;  // 4718592
  constexpr size_t SZ_M   = (size_t)N_ * FF_ * 2;      // 18874368
  constexpr int    WELEM  = D3_ * D_ + D_ * D_ + FF_ * D_ + D_ * FF_;  // 7077888

  float* xbuf = (float*)ws;
  u16* hbuf  = (u16*)(ws + SZ_X);
  u16* qbuf  = (u16*)(ws + SZ_X + SZ_H);
  u16* kbuf  = (u16*)(ws + SZ_X + SZ_H + SZ_QKV);
  u16* vtbuf = (u16*)(ws + SZ_X + SZ_H + 2 * SZ_QKV);
  u16* cbuf  = (u16*)(ws + SZ_X + SZ_H + 3 * SZ_QKV);
  u16* mbuf  = (u16*)(ws + SZ_X + SZ_H + 4 * SZ_QKV);
  u16* wbf   = (u16*)(ws + SZ_X + SZ_H + 4 * SZ_QKV + SZ_M);

  // both layers' weights in one conversion launch
  convert_weights_kernel<<<dim3(WELEM / 4 / 256, 2), 256, 0, stream>>>(
      (const float*)d_in[7],  (const float*)d_in[9],
      (const float*)d_in[13], (const float*)d_in[15],
      (const float*)d_in[19], (const float*)d_in[21],
      (const float*)d_in[25], (const float*)d_in[27], wbf);

  // embedding + layer0 LN1 fused
  embed_ln_kernel<<<N_ / 4, 256, 0, stream>>>(
      ids, pos, wte, wpe, (const float*)d_in[5], (const float*)d_in[6], xbuf, hbuf);

  for (int l = 0; l < 2; ++l) {
    int p = 5 + l * 12;
    const float* ln1w  = (const float*)d_in[p + 0];
    const float* ln1b  = (const float*)d_in[p + 1];
    const float* bqkv  = (const float*)d_in[p + 3];
    const float* bo    = (const float*)d_in[p + 5];
    const float* ln2w  = (const float*)d_in[p + 6];
    const float* ln2b  = (const float*)d_in[p + 7];
    const float* bfc   = (const float*)d_in[p + 9];
    const float* bproj = (const float*)d_in[p + 11];

    u16* wb = wbf + (size_t)l * WELEM;
    u16* wqkv_b  = wb;
    u16* wo_b    = wb + D3_ * D_;
    u16* wfc_b   = wb + D3_ * D_ + D_ * D_;
    u16* wproj_b = wb + D3_ * D_ + D_ * D_ + FF_ * D_;

    if (l > 0) {
      // LN1 -> h (layer 0's is fused into embed_ln_kernel)
      ln_kernel<u16><<<N_ / 4, 256, 0, stream>>>(xbuf, ln1w, ln1b, hbuf);
    }
    // QKV: (3072 x 768) @ (2304 x 768)^T, scatter to q/k/vt (q pre-scaled)
    gemm_kernel<128, 128, 0><<<dim3(N_ / 128, D3_ / 128), 256, 0, stream>>>(
        hbuf, wqkv_b, bqkv, D_, qbuf, kbuf, vtbuf, nullptr);
    // attention -> ctx
    attn_kernel<<<dim3(S_ / 64, B_ * H_), 256, 0, stream>>>(qbuf, kbuf, vtbuf, cbuf);
    // WO + residual -> x
    gemm_kernel<128, 64, 1><<<dim3(N_ / 128, D_ / 64), 256, 0, stream>>>(
        cbuf, wo_b, bo, D_, nullptr, nullptr, nullptr, xbuf);
    // LN2 -> h
    ln_kernel<u16><<<N_ / 4, 256, 0, stream>>>(xbuf, ln2w, ln2b, hbuf);
    // FC + GELU -> m
    gemm_kernel<128, 128, 2><<<dim3(N_ / 128, FF_ / 128), 256, 0, stream>>>(
        hbuf, wfc_b, bfc, D_, mbuf, nullptr, nullptr, nullptr);
    // PROJ + residual -> x
    gemm_kernel<128, 64, 1><<<dim3(N_ / 128, D_ / 64), 256, 0, stream>>>(
        mbuf, wproj_b, bproj, FF_, nullptr, nullptr, nullptr, xbuf);
  }

  // final LN -> d_out (fp32)
  ln_kernel<float><<<N_ / 4, 256, 0, stream>>>(xbuf, lnf_w, lnf_b, (float*)d_out);
}